// Round 2
// baseline (855.685 us; speedup 1.0000x reference)
//
#include <hip/hip_runtime.h>
#include <hip/hip_bf16.h>

#define F_OUT 64
#define NEG_SLOPE 0.2f
#define SOFT_EPS 1e-16f

// ---------- runtime dtype detection ----------
// flags[0] = 1 if float tensors are bf16, 0 if float32
// flags[1] = 1 if edge_index is int64, 0 if int32
__global__ void detect_dtypes(const unsigned* __restrict__ wbits,
                              const unsigned* __restrict__ ebits,
                              int* __restrict__ flags) {
    __shared__ int cnt_bf, cnt_zero;
    if (threadIdx.x == 0) { cnt_bf = 0; cnt_zero = 0; }
    __syncthreads();
    int lb = 0, lz = 0;
    // W1 has >= 8192 elements -> >= 16 KiB -> 4096 u32 words safe to read.
    // edge_index has >= 1.6M elements -> >= 6.4 MB -> 8192 words safe.
    for (int k = threadIdx.x; k < 4096; k += 256) {
        unsigned w = wbits[k];
        unsigned e = (w >> 7) & 0xFFu;      // exponent field of low-half bf16
        if (e >= 0x60u && e <= 0x7Eu) lb++; // plausible glorot magnitude
        if (ebits[2 * k + 1] == 0u) lz++;   // int64 high words are all zero
    }
    atomicAdd(&cnt_bf, lb);
    atomicAdd(&cnt_zero, lz);
    __syncthreads();
    if (threadIdx.x == 0) {
        flags[0] = (cnt_bf > 2048) ? 1 : 0;
        flags[1] = (cnt_zero > 2048) ? 1 : 0;
    }
}

// Convert the small weight tensors to f32 scratch (uniform branch on flag).
__global__ void conv_weights(const void* w1, const void* as1, const void* ad1, const void* b1,
                             const void* w2, const void* as2, const void* ad2, const void* b2,
                             float* __restrict__ out, int n1, int n2,
                             const int* __restrict__ flags) {
    int t = blockIdx.x * blockDim.x + threadIdx.x;
    int total = n1 + n2 + 6 * 64;
    if (t >= total) return;
    const void* src; int off;
    if (t < n1)                { src = w1;  off = t; }
    else if (t < n1 + 64)      { src = as1; off = t - n1; }
    else if (t < n1 + 128)     { src = ad1; off = t - n1 - 64; }
    else if (t < n1 + 192)     { src = b1;  off = t - n1 - 128; }
    else if (t < n1 + 192 + n2){ src = w2;  off = t - n1 - 192; }
    else if (t < n1 + 256 + n2){ src = as2; off = t - n1 - 192 - n2; }
    else if (t < n1 + 320 + n2){ src = ad2; off = t - n1 - 256 - n2; }
    else                       { src = b2;  off = t - n1 - 320 - n2; }
    float v = flags[0] ? __bfloat162float(((const __hip_bfloat16*)src)[off])
                       : ((const float*)src)[off];
    out[t] = v;
}

// h = x @ W, fused a_src = h.att_s, a_dst = h.att_d. One wave per row.
__global__ void gemm_attn(const void* __restrict__ xv, const float* __restrict__ W,
                          const float* __restrict__ att_s, const float* __restrict__ att_d,
                          float* __restrict__ h, float* __restrict__ a_s,
                          float* __restrict__ a_d, int N, int K,
                          const int* __restrict__ flags, int use_flag) {
    int lane = threadIdx.x & 63;
    int row = blockIdx.x * 4 + (threadIdx.x >> 6);
    if (row >= N) return;
    int bf = use_flag ? flags[0] : 0;
    float acc = 0.f;
    if (bf) {
        const __hip_bfloat16* xr = (const __hip_bfloat16*)xv + (size_t)row * K;
        for (int k = 0; k < K; ++k)
            acc += __bfloat162float(xr[k]) * W[k * F_OUT + lane];
    } else {
        const float* xr = (const float*)xv + (size_t)row * K;
        for (int k = 0; k < K; ++k)
            acc += xr[k] * W[k * F_OUT + lane];
    }
    h[row * F_OUT + lane] = acc;
    float vs = acc * att_s[lane];
    float vd = acc * att_d[lane];
#pragma unroll
    for (int off = 32; off; off >>= 1) {
        vs += __shfl_down(vs, off);
        vd += __shfl_down(vd, off);
    }
    if (lane == 0) { a_s[row] = vs; a_d[row] = vd; }
}

__device__ __forceinline__ int get_idx(const void* ei, int i64, long long pos) {
    return i64 ? (int)((const long long*)ei)[pos] : ((const int*)ei)[pos];
}

// s[i] += exp(leaky_relu(a_s[j] + a_d[i])), self-loops at t >= E
__global__ void edge_softmax_sum(const void* __restrict__ ei,
                                 const float* __restrict__ a_s, const float* __restrict__ a_d,
                                 float* __restrict__ s, int E, int N,
                                 const int* __restrict__ flags) {
    int t = blockIdx.x * blockDim.x + threadIdx.x;
    if (t >= E + N) return;
    int i64 = flags[1];
    int j = t < E ? get_idx(ei, i64, t) : t - E;
    int i = t < E ? get_idx(ei, i64, (long long)E + t) : t - E;
    float e = a_s[j] + a_d[i];
    float v = e > 0.f ? e : NEG_SLOPE * e;
    atomicAdd(&s[i], __expf(v));
}

// 64 lanes per edge: acc[i][f] += alpha * h[j][f]
__global__ void edge_accum(const void* __restrict__ ei,
                           const float* __restrict__ a_s, const float* __restrict__ a_d,
                           const float* __restrict__ s, const float* __restrict__ h,
                           float* __restrict__ acc, int E, int N,
                           const int* __restrict__ flags) {
    long long t = (long long)blockIdx.x * blockDim.x + threadIdx.x;
    long long edge = t >> 6;
    int f = (int)(t & 63);
    if (edge >= E + N) return;
    int i64 = flags[1];
    int j = edge < E ? get_idx(ei, i64, edge) : (int)(edge - E);
    int i = edge < E ? get_idx(ei, i64, (long long)E + edge) : (int)(edge - E);
    float e = a_s[j] + a_d[i];
    float v = e > 0.f ? e : NEG_SLOPE * e;
    float alpha = __expf(v) / (s[i] + SOFT_EPS);
    atomicAdd(&acc[i * F_OUT + f], alpha * h[j * F_OUT + f]);
}

__global__ void finalize_relu(const float* __restrict__ acc, const float* __restrict__ b,
                              float* __restrict__ x1, int N) {
    int t = blockIdx.x * blockDim.x + threadIdx.x;
    if (t >= N * F_OUT) return;
    float v = acc[t] + b[t & 63];
    x1[t] = v > 0.f ? v : 0.f;
}

__global__ void finalize_out(const float* __restrict__ acc, const float* __restrict__ b,
                             void* __restrict__ out, int N,
                             const int* __restrict__ flags) {
    int t = blockIdx.x * blockDim.x + threadIdx.x;
    if (t >= N * F_OUT) return;
    float v = acc[t] + b[t & 63];
    if (flags[0]) ((__hip_bfloat16*)out)[t] = __float2bfloat16(v);
    else          ((float*)out)[t] = v;
}

extern "C" void kernel_launch(void* const* d_in, const int* in_sizes, int n_in,
                              void* d_out, int out_size, void* d_ws, size_t ws_size,
                              hipStream_t stream) {
    const void* x   = d_in[0];
    const void* ei  = d_in[1];
    const void* W1  = d_in[2];
    const void* as1 = d_in[3];
    const void* ad1 = d_in[4];
    const void* b1  = d_in[5];
    const void* W2  = d_in[6];
    const void* as2 = d_in[7];
    const void* ad2 = d_in[8];
    const void* b2  = d_in[9];

    int E  = in_sizes[1] / 2;          // 800000
    int n1 = in_sizes[2];              // 128*64
    int n2 = in_sizes[6];              // 64*64
    int K1 = n1 / F_OUT;               // 128
    int N  = in_sizes[0] / K1;         // 50000

    size_t nf = (size_t)N * F_OUT;     // 3.2M
    float* ws  = (float*)d_ws;
    float* h   = ws;                    // nf
    float* acc = ws + nf;               // nf
    float* x1  = ws + 2 * nf;           // nf
    float* a_s = ws + 3 * nf;           // N
    float* a_d = a_s + N;               // N
    float* s   = a_d + N;               // N
    float* cw  = s + N;                 // n1 + n2 + 384
    int* flags = (int*)(cw + n1 + n2 + 6 * 64);

    float* cW1 = cw;
    float* cAs1 = cw + n1, *cAd1 = cAs1 + 64, *cB1 = cAd1 + 64;
    float* cW2 = cB1 + 64;
    float* cAs2 = cW2 + n2, *cAd2 = cAs2 + 64, *cB2 = cAd2 + 64;

    int total = E + N;
    int blkRow  = (N + 3) / 4;
    int blkEdge = (total + 255) / 256;
    long long featThreads = (long long)total * F_OUT;
    int blkFeat = (int)((featThreads + 255) / 256);
    int blkNode = (int)((nf + 255) / 256);
    int blkConv = (n1 + n2 + 384 + 255) / 256;

    detect_dtypes<<<1, 256, 0, stream>>>((const unsigned*)W1, (const unsigned*)ei, flags);
    conv_weights<<<blkConv, 256, 0, stream>>>(W1, as1, ad1, b1, W2, as2, ad2, b2,
                                              cw, n1, n2, flags);

    // ---- layer 1 ----
    hipMemsetAsync(acc, 0, nf * sizeof(float), stream);
    hipMemsetAsync(s, 0, N * sizeof(float), stream);
    gemm_attn<<<blkRow, 256, 0, stream>>>(x, cW1, cAs1, cAd1, h, a_s, a_d, N, K1, flags, 1);
    edge_softmax_sum<<<blkEdge, 256, 0, stream>>>(ei, a_s, a_d, s, E, N, flags);
    edge_accum<<<blkFeat, 256, 0, stream>>>(ei, a_s, a_d, s, h, acc, E, N, flags);
    finalize_relu<<<blkNode, 256, 0, stream>>>(acc, cB1, x1, N);

    // ---- layer 2 ----
    hipMemsetAsync(acc, 0, nf * sizeof(float), stream);
    hipMemsetAsync(s, 0, N * sizeof(float), stream);
    gemm_attn<<<blkRow, 256, 0, stream>>>(x1, cW2, cAs2, cAd2, h, a_s, a_d, N, F_OUT, flags, 0);
    edge_softmax_sum<<<blkEdge, 256, 0, stream>>>(ei, a_s, a_d, s, E, N, flags);
    edge_accum<<<blkFeat, 256, 0, stream>>>(ei, a_s, a_d, s, h, acc, E, N, flags);
    finalize_out<<<blkNode, 256, 0, stream>>>(acc, cB2, d_out, N, flags);
}

// Round 3
// 556.608 us; speedup vs baseline: 1.5373x; 1.5373x over previous
//
#include <hip/hip_runtime.h>
#include <hip/hip_bf16.h>

#define F_OUT 64
#define NEG_SLOPE 0.2f
#define SOFT_EPS 1e-16f

// ---------- runtime dtype detection ----------
// flags[0] = 1 if float tensors are bf16, 0 if float32
// flags[1] = 1 if edge_index is int64, 0 if int32
__global__ void detect_dtypes(const unsigned* __restrict__ wbits,
                              const unsigned* __restrict__ ebits,
                              int* __restrict__ flags) {
    __shared__ int cnt_bf, cnt_zero;
    if (threadIdx.x == 0) { cnt_bf = 0; cnt_zero = 0; }
    __syncthreads();
    int lb = 0, lz = 0;
    for (int k = threadIdx.x; k < 4096; k += 256) {
        unsigned w = wbits[k];
        unsigned e = (w >> 7) & 0xFFu;
        if (e >= 0x60u && e <= 0x7Eu) lb++;
        if (ebits[2 * k + 1] == 0u) lz++;
    }
    atomicAdd(&cnt_bf, lb);
    atomicAdd(&cnt_zero, lz);
    __syncthreads();
    if (threadIdx.x == 0) {
        flags[0] = (cnt_bf > 2048) ? 1 : 0;
        flags[1] = (cnt_zero > 2048) ? 1 : 0;
    }
}

__global__ void conv_weights(const void* w1, const void* as1, const void* ad1, const void* b1,
                             const void* w2, const void* as2, const void* ad2, const void* b2,
                             float* __restrict__ out, int n1, int n2,
                             const int* __restrict__ flags) {
    int t = blockIdx.x * blockDim.x + threadIdx.x;
    int total = n1 + n2 + 6 * 64;
    if (t >= total) return;
    const void* src; int off;
    if (t < n1)                { src = w1;  off = t; }
    else if (t < n1 + 64)      { src = as1; off = t - n1; }
    else if (t < n1 + 128)     { src = ad1; off = t - n1 - 64; }
    else if (t < n1 + 192)     { src = b1;  off = t - n1 - 128; }
    else if (t < n1 + 192 + n2){ src = w2;  off = t - n1 - 192; }
    else if (t < n1 + 256 + n2){ src = as2; off = t - n1 - 192 - n2; }
    else if (t < n1 + 320 + n2){ src = ad2; off = t - n1 - 256 - n2; }
    else                       { src = b2;  off = t - n1 - 320 - n2; }
    float v = flags[0] ? __bfloat162float(((const __hip_bfloat16*)src)[off])
                       : ((const float*)src)[off];
    out[t] = v;
}

__device__ __forceinline__ int get_idx(const void* ei, int i64, long long pos) {
    return i64 ? (int)((const long long*)ei)[pos] : ((const int*)ei)[pos];
}

// ---------- CSR build (by destination), self-loops appended at t >= E ----------
__global__ void hist_deg(const void* __restrict__ ei, int* __restrict__ deg,
                         int E, int N, const int* __restrict__ flags) {
    int t = blockIdx.x * blockDim.x + threadIdx.x;
    if (t >= E + N) return;
    int i64 = flags[1];
    int i = t < E ? get_idx(ei, i64, (long long)E + t) : t - E;
    atomicAdd(&deg[i], 1);
}

// single block of 1024 threads: exclusive scan deg -> row_ptr[0..N]
__global__ void scan_deg(const int* __restrict__ deg, int* __restrict__ row_ptr, int N) {
    __shared__ int part[1024];
    int tid = threadIdx.x;
    int chunk = (N + 1023) >> 10;
    int s = tid * chunk;
    int e = s + chunk < N ? s + chunk : N;
    int sum = 0;
    for (int k = s; k < e; ++k) sum += deg[k];
    part[tid] = sum;
    __syncthreads();
    for (int off = 1; off < 1024; off <<= 1) {
        int v = (tid >= off) ? part[tid - off] : 0;
        __syncthreads();
        part[tid] += v;
        __syncthreads();
    }
    int run = (tid > 0) ? part[tid - 1] : 0;
    for (int k = s; k < e; ++k) { row_ptr[k] = run; run += deg[k]; }
    if (tid == 1023) row_ptr[N] = part[1023];
}

__global__ void scatter_edges(const void* __restrict__ ei, const int* __restrict__ row_ptr,
                              int* __restrict__ cursor, int* __restrict__ eidx,
                              int E, int N, const int* __restrict__ flags) {
    int t = blockIdx.x * blockDim.x + threadIdx.x;
    if (t >= E + N) return;
    int i64 = flags[1];
    int i = t < E ? get_idx(ei, i64, (long long)E + t) : t - E;
    int j = t < E ? get_idx(ei, i64, t) : t - E;
    int p = atomicAdd(&cursor[i], 1);
    eidx[row_ptr[i] + p] = j;
}

// ---------- h = x @ W fused with attention dots; 4 rows per wave ----------
template <int KK>
__global__ void gemm_attn(const void* __restrict__ xv, const float* __restrict__ W,
                          const float* __restrict__ att_s, const float* __restrict__ att_d,
                          float* __restrict__ h, float* __restrict__ a_s,
                          float* __restrict__ a_d, int N,
                          const int* __restrict__ flags, int maybe_bf16) {
    int lane = threadIdx.x & 63;
    int row0 = (blockIdx.x * 4 + (threadIdx.x >> 6)) * 4;
    if (row0 >= N) return;
    int bf = maybe_bf16 ? flags[0] : 0;
    float xa[4], xb[4];
#pragma unroll
    for (int r = 0; r < 4; ++r) {
        int row = (row0 + r < N) ? row0 + r : N - 1;
        if (bf) {
            const __hip_bfloat16* xr = (const __hip_bfloat16*)xv + (size_t)row * KK;
            xa[r] = __bfloat162float(xr[lane]);
            xb[r] = (KK == 128) ? __bfloat162float(xr[64 + lane]) : 0.f;
        } else {
            const float* xr = (const float*)xv + (size_t)row * KK;
            xa[r] = xr[lane];
            xb[r] = (KK == 128) ? xr[64 + lane] : 0.f;
        }
    }
    float acc[4] = {0.f, 0.f, 0.f, 0.f};
#pragma unroll 8
    for (int k = 0; k < 64; ++k) {
        float w = W[k * F_OUT + lane];
#pragma unroll
        for (int r = 0; r < 4; ++r) acc[r] += __shfl(xa[r], k) * w;
    }
    if (KK == 128) {
#pragma unroll 8
        for (int k = 0; k < 64; ++k) {
            float w = W[(64 + k) * F_OUT + lane];
#pragma unroll
            for (int r = 0; r < 4; ++r) acc[r] += __shfl(xb[r], k) * w;
        }
    }
#pragma unroll
    for (int r = 0; r < 4; ++r) {
        int row = row0 + r;
        if (row < N) {
            h[(size_t)row * F_OUT + lane] = acc[r];
            float vs = acc[r] * att_s[lane];
            float vd = acc[r] * att_d[lane];
#pragma unroll
            for (int off = 32; off; off >>= 1) {
                vs += __shfl_xor(vs, off);
                vd += __shfl_xor(vd, off);
            }
            if (lane == 0) { a_s[row] = vs; a_d[row] = vd; }
        }
    }
}

// ---------- fused softmax + gather + bias (+relu / bf16 store); 1 wave per node ----------
// mode 0: out_f32 = relu(acc/sum + bias)   (layer 1 -> x1)
// mode 1: out = acc/sum + bias, stored bf16 or f32 per flags[0]  (layer 2 -> d_out)
__global__ void node_gather(const int* __restrict__ row_ptr, const int* __restrict__ eidx,
                            const float* __restrict__ a_s, const float* __restrict__ a_d,
                            const float* __restrict__ h, const float* __restrict__ bias,
                            void* __restrict__ out, int N,
                            const int* __restrict__ flags, int mode) {
    int lane = threadIdx.x & 63;
    int i = blockIdx.x * 4 + (threadIdx.x >> 6);
    if (i >= N) return;
    int beg = row_ptr[i];
    int end = row_ptr[i + 1];
    float ad = a_d[i];
    float se = 0.f, acc = 0.f;
    for (int p = beg; p < end; ++p) {
        int j = eidx[p];
        float e = a_s[j] + ad;
        float v = e > 0.f ? e : NEG_SLOPE * e;
        float w = __expf(v);
        se += w;
        acc += w * h[(size_t)j * F_OUT + lane];
    }
    float v = acc / (se + SOFT_EPS) + bias[lane];
    if (mode == 0) {
        ((float*)out)[(size_t)i * F_OUT + lane] = v > 0.f ? v : 0.f;
    } else {
        if (flags[0]) ((__hip_bfloat16*)out)[(size_t)i * F_OUT + lane] = __float2bfloat16(v);
        else          ((float*)out)[(size_t)i * F_OUT + lane] = v;
    }
}

extern "C" void kernel_launch(void* const* d_in, const int* in_sizes, int n_in,
                              void* d_out, int out_size, void* d_ws, size_t ws_size,
                              hipStream_t stream) {
    const void* x   = d_in[0];
    const void* ei  = d_in[1];
    const void* W1  = d_in[2];
    const void* as1 = d_in[3];
    const void* ad1 = d_in[4];
    const void* b1  = d_in[5];
    const void* W2  = d_in[6];
    const void* as2 = d_in[7];
    const void* ad2 = d_in[8];
    const void* b2  = d_in[9];

    int E  = in_sizes[1] / 2;          // 800000
    int n1 = in_sizes[2];              // 128*64
    int n2 = in_sizes[6];              // 64*64
    int K1 = n1 / F_OUT;               // 128
    int N  = in_sizes[0] / K1;         // 50000
    int total = E + N;

    size_t nf = (size_t)N * F_OUT;
    float* ws  = (float*)d_ws;
    float* h   = ws;                    // nf
    float* x1  = ws + nf;               // nf
    float* a_s = ws + 2 * nf;           // N
    float* a_d = a_s + N;               // N
    float* cw  = a_d + N;               // n1+n2+384
    float* cW1 = cw;
    float* cAs1 = cw + n1, *cAd1 = cAs1 + 64, *cB1 = cAd1 + 64;
    float* cW2 = cB1 + 64;
    float* cAs2 = cW2 + n2, *cAd2 = cAs2 + 64, *cB2 = cAd2 + 64;
    int* flags   = (int*)(cB2 + 64);
    int* deg     = flags + 8;           // N
    int* cursor  = deg + N;             // N  (contiguous with deg for one memset)
    int* row_ptr = cursor + N;          // N+1
    int* eidx    = row_ptr + N + 1;     // E+N

    int blkEdge = (total + 255) / 256;
    int blkConv = (n1 + n2 + 384 + 255) / 256;
    int blkGemm = (N + 15) / 16;
    int blkNode = (N + 3) / 4;

    detect_dtypes<<<1, 256, 0, stream>>>((const unsigned*)W1, (const unsigned*)ei, flags);
    conv_weights<<<blkConv, 256, 0, stream>>>(W1, as1, ad1, b1, W2, as2, ad2, b2,
                                              cw, n1, n2, flags);

    // ---- CSR build (shared by both layers) ----
    hipMemsetAsync(deg, 0, 2 * N * sizeof(int), stream);   // deg + cursor
    hist_deg<<<blkEdge, 256, 0, stream>>>(ei, deg, E, N, flags);
    scan_deg<<<1, 1024, 0, stream>>>(deg, row_ptr, N);
    scatter_edges<<<blkEdge, 256, 0, stream>>>(ei, row_ptr, cursor, eidx, E, N, flags);

    // ---- layer 1 ----
    gemm_attn<128><<<blkGemm, 256, 0, stream>>>(x, cW1, cAs1, cAd1, h, a_s, a_d, N, flags, 1);
    node_gather<<<blkNode, 256, 0, stream>>>(row_ptr, eidx, a_s, a_d, h, cB1, x1, N, flags, 0);

    // ---- layer 2 ----
    gemm_attn<64><<<blkGemm, 256, 0, stream>>>(x1, cW2, cAs2, cAd2, h, a_s, a_d, N, flags, 0);
    node_gather<<<blkNode, 256, 0, stream>>>(row_ptr, eidx, a_s, a_d, h, cB2, d_out, N, flags, 1);
}

// Round 4
// 379.224 us; speedup vs baseline: 2.2564x; 1.4678x over previous
//
#include <hip/hip_runtime.h>
#include <hip/hip_bf16.h>

#define F_OUT 64
#define NEG_SLOPE 0.2f
#define SOFT_EPS 1e-16f

typedef short short8 __attribute__((ext_vector_type(8)));
typedef float floatx4 __attribute__((ext_vector_type(4)));

__device__ __forceinline__ unsigned short f2bf_bits(float v) {
    __hip_bfloat16 hb = __float2bfloat16(v);
    return *(unsigned short*)&hb;
}
__device__ __forceinline__ float bf_bits2f(unsigned short u) {
    __hip_bfloat16 hb = *(__hip_bfloat16*)&u;
    return __bfloat162float(hb);
}

// ---------- runtime dtype detection ----------
// flags[0] = 1 if float tensors are bf16, 0 if float32
// flags[1] = 1 if edge_index is int64, 0 if int32
__global__ void detect_dtypes(const unsigned* __restrict__ wbits,
                              const unsigned* __restrict__ ebits,
                              int* __restrict__ flags) {
    __shared__ int cnt_bf, cnt_zero;
    if (threadIdx.x == 0) { cnt_bf = 0; cnt_zero = 0; }
    __syncthreads();
    int lb = 0, lz = 0;
    for (int k = threadIdx.x; k < 4096; k += 256) {
        unsigned w = wbits[k];
        unsigned e = (w >> 7) & 0xFFu;
        if (e >= 0x60u && e <= 0x7Eu) lb++;
        if (ebits[2 * k + 1] == 0u) lz++;
    }
    atomicAdd(&cnt_bf, lb);
    atomicAdd(&cnt_zero, lz);
    __syncthreads();
    if (threadIdx.x == 0) {
        flags[0] = (cnt_bf > 2048) ? 1 : 0;
        flags[1] = (cnt_zero > 2048) ? 1 : 0;
    }
}

__device__ __forceinline__ float read_any(const void* src, int off, int bf) {
    return bf ? __bfloat162float(((const __hip_bfloat16*)src)[off])
              : ((const float*)src)[off];
}

// Transpose W1,W2 -> bf16 Wt[n][k]; convert att/bias vectors to f32.
__global__ void prep_weights(const void* w1, const void* as1, const void* ad1, const void* b1,
                             const void* w2, const void* as2, const void* ad2, const void* b2,
                             unsigned short* __restrict__ wt1, unsigned short* __restrict__ wt2,
                             float* __restrict__ vecs, int n1, int n2, int K1,
                             const int* __restrict__ flags) {
    int t = blockIdx.x * blockDim.x + threadIdx.x;
    int bf = flags[0];
    if (t < n1) {                       // wt1[n*K1 + k] = W1[k*64 + n]
        int n = t / K1, k = t - n * K1;
        wt1[t] = f2bf_bits(read_any(w1, k * F_OUT + n, bf));
    } else if (t < n1 + n2) {           // wt2[n*64 + k] = W2[k*64 + n]
        int u = t - n1;
        int n = u >> 6, k = u & 63;
        wt2[u] = f2bf_bits(read_any(w2, k * F_OUT + n, bf));
    } else if (t < n1 + n2 + 384) {
        int u = t - n1 - n2;
        const void* src[6] = {as1, ad1, b1, as2, ad2, b2};
        vecs[u] = read_any(src[u >> 6], u & 63, bf);
    }
}

__device__ __forceinline__ int get_idx(const void* ei, int i64, long long pos) {
    return i64 ? (int)((const long long*)ei)[pos] : ((const int*)ei)[pos];
}

// ---------- CSR build (by destination), self-loops appended at t >= E ----------
__global__ void hist_deg(const void* __restrict__ ei, int* __restrict__ deg,
                         int E, int N, const int* __restrict__ flags) {
    int t = blockIdx.x * blockDim.x + threadIdx.x;
    if (t >= E + N) return;
    int i64 = flags[1];
    int i = t < E ? get_idx(ei, i64, (long long)E + t) : t - E;
    atomicAdd(&deg[i], 1);
}

__global__ void scan_deg(const int* __restrict__ deg, int* __restrict__ row_ptr, int N) {
    __shared__ int part[1024];
    int tid = threadIdx.x;
    int chunk = (N + 1023) >> 10;
    int s = tid * chunk;
    int e = s + chunk < N ? s + chunk : N;
    int sum = 0;
    for (int k = s; k < e; ++k) sum += deg[k];
    part[tid] = sum;
    __syncthreads();
    for (int off = 1; off < 1024; off <<= 1) {
        int v = (tid >= off) ? part[tid - off] : 0;
        __syncthreads();
        part[tid] += v;
        __syncthreads();
    }
    int run = (tid > 0) ? part[tid - 1] : 0;
    for (int k = s; k < e; ++k) { row_ptr[k] = run; run += deg[k]; }
    if (tid == 1023) row_ptr[N] = part[1023];
}

__global__ void scatter_edges(const void* __restrict__ ei, const int* __restrict__ row_ptr,
                              int* __restrict__ cursor, int* __restrict__ eidx,
                              int E, int N, const int* __restrict__ flags) {
    int t = blockIdx.x * blockDim.x + threadIdx.x;
    if (t >= E + N) return;
    int i64 = flags[1];
    int i = t < E ? get_idx(ei, i64, (long long)E + t) : t - E;
    int j = t < E ? get_idx(ei, i64, t) : t - E;
    int p = atomicAdd(&cursor[i], 1);
    eidx[row_ptr[i] + p] = j;
}

// ---------- MFMA GEMM: h = x @ W (h stored bf16), fused attention dots ----------
// One wave = 16 rows x 64 cols. in_mode: 0=f32, 1=bf16, 2=consult flags[0].
template <int K>
__global__ void mfma_gemm(const void* __restrict__ xv, const unsigned short* __restrict__ Wt,
                          const float* __restrict__ att_s, const float* __restrict__ att_d,
                          unsigned short* __restrict__ h, float* __restrict__ a_s,
                          float* __restrict__ a_d, int N,
                          const int* __restrict__ flags, int in_mode) {
    int lane = threadIdx.x & 63;
    int m0 = (blockIdx.x * 4 + (threadIdx.x >> 6)) * 16;
    if (m0 >= N) return;
    int c = lane & 15, quad = lane >> 4;
    int arow = m0 + c;
    if (arow >= N) arow = N - 1;         // clamp loads; stores are guarded
    int bf = (in_mode == 2) ? flags[0] : in_mode;

    floatx4 acc0 = {0.f, 0.f, 0.f, 0.f};
    floatx4 acc1 = acc0, acc2 = acc0, acc3 = acc0;

    for (int kc = 0; kc < K; kc += 32) {
        int ka = kc + quad * 8;
        short8 a;
        if (bf) {
            a = *(const short8*)((const unsigned short*)xv + (size_t)arow * K + ka);
        } else {
            const float* xp = (const float*)xv + (size_t)arow * K + ka;
#pragma unroll
            for (int j = 0; j < 8; ++j) a[j] = (short)f2bf_bits(xp[j]);
        }
        short8 b0 = *(const short8*)(Wt + (size_t)(c)      * K + ka);
        short8 b1 = *(const short8*)(Wt + (size_t)(16 + c) * K + ka);
        short8 b2 = *(const short8*)(Wt + (size_t)(32 + c) * K + ka);
        short8 b3 = *(const short8*)(Wt + (size_t)(48 + c) * K + ka);
        acc0 = __builtin_amdgcn_mfma_f32_16x16x32_bf16(a, b0, acc0, 0, 0, 0);
        acc1 = __builtin_amdgcn_mfma_f32_16x16x32_bf16(a, b1, acc1, 0, 0, 0);
        acc2 = __builtin_amdgcn_mfma_f32_16x16x32_bf16(a, b2, acc2, 0, 0, 0);
        acc3 = __builtin_amdgcn_mfma_f32_16x16x32_bf16(a, b3, acc3, 0, 0, 0);
    }

    float as0 = att_s[c],      as1 = att_s[16 + c], as2 = att_s[32 + c], as3 = att_s[48 + c];
    float ad0 = att_d[c],      ad1 = att_d[16 + c], ad2 = att_d[32 + c], ad3 = att_d[48 + c];
#pragma unroll
    for (int reg = 0; reg < 3 + 1; ++reg) {
        int row = m0 + quad * 4 + reg;
        float vs = acc0[reg] * as0 + acc1[reg] * as1 + acc2[reg] * as2 + acc3[reg] * as3;
        float vd = acc0[reg] * ad0 + acc1[reg] * ad1 + acc2[reg] * ad2 + acc3[reg] * ad3;
#pragma unroll
        for (int off = 1; off < 16; off <<= 1) {
            vs += __shfl_xor(vs, off);
            vd += __shfl_xor(vd, off);
        }
        if (row < N) {
            if (c == 0) { a_s[row] = vs; a_d[row] = vd; }
            unsigned short* hr = h + (size_t)row * F_OUT + c;
            hr[0]  = f2bf_bits(acc0[reg]);
            hr[16] = f2bf_bits(acc1[reg]);
            hr[32] = f2bf_bits(acc2[reg]);
            hr[48] = f2bf_bits(acc3[reg]);
        }
    }
}

// ---------- fused softmax + gather + bias; 1 wave per node ----------
// mode 0: x1_bf16 = bf16(relu(acc/sum + bias))
// mode 1: out = acc/sum + bias, stored bf16 or f32 per flags[0]
__global__ void node_gather(const int* __restrict__ row_ptr, const int* __restrict__ eidx,
                            const float* __restrict__ a_s, const float* __restrict__ a_d,
                            const unsigned short* __restrict__ h, const float* __restrict__ bias,
                            void* __restrict__ out, int N,
                            const int* __restrict__ flags, int mode) {
    int lane = threadIdx.x & 63;
    int i = blockIdx.x * 4 + (threadIdx.x >> 6);
    if (i >= N) return;
    int beg = row_ptr[i];
    int end = row_ptr[i + 1];
    float ad = a_d[i];
    float se = 0.f, acc = 0.f;
    int p = beg;
    for (; p + 2 <= end; p += 2) {
        int j0 = eidx[p], j1 = eidx[p + 1];
        float e0 = a_s[j0] + ad, e1 = a_s[j1] + ad;
        float h0 = bf_bits2f(h[(size_t)j0 * F_OUT + lane]);
        float h1 = bf_bits2f(h[(size_t)j1 * F_OUT + lane]);
        float w0 = __expf(e0 > 0.f ? e0 : NEG_SLOPE * e0);
        float w1 = __expf(e1 > 0.f ? e1 : NEG_SLOPE * e1);
        se += w0 + w1;
        acc += w0 * h0 + w1 * h1;
    }
    if (p < end) {
        int j = eidx[p];
        float e = a_s[j] + ad;
        float w = __expf(e > 0.f ? e : NEG_SLOPE * e);
        se += w;
        acc += w * bf_bits2f(h[(size_t)j * F_OUT + lane]);
    }
    float v = acc / (se + SOFT_EPS) + bias[lane];
    if (mode == 0) {
        ((unsigned short*)out)[(size_t)i * F_OUT + lane] = f2bf_bits(v > 0.f ? v : 0.f);
    } else {
        if (flags[0]) ((__hip_bfloat16*)out)[(size_t)i * F_OUT + lane] = __float2bfloat16(v);
        else          ((float*)out)[(size_t)i * F_OUT + lane] = v;
    }
}

extern "C" void kernel_launch(void* const* d_in, const int* in_sizes, int n_in,
                              void* d_out, int out_size, void* d_ws, size_t ws_size,
                              hipStream_t stream) {
    const void* x   = d_in[0];
    const void* ei  = d_in[1];
    const void* W1  = d_in[2];
    const void* as1 = d_in[3];
    const void* ad1 = d_in[4];
    const void* b1  = d_in[5];
    const void* W2  = d_in[6];
    const void* as2 = d_in[7];
    const void* ad2 = d_in[8];
    const void* b2  = d_in[9];

    int E  = in_sizes[1] / 2;          // 800000
    int n1 = in_sizes[2];              // 128*64
    int n2 = in_sizes[6];              // 64*64
    int K1 = n1 / F_OUT;               // 128
    int N  = in_sizes[0] / K1;         // 50000
    int total = E + N;

    size_t nf = (size_t)N * F_OUT;
    char* wsb = (char*)d_ws;
    unsigned short* h   = (unsigned short*)wsb;                 // nf bf16
    unsigned short* x1b = h + nf;                               // nf bf16
    unsigned short* wt1 = x1b + nf;                             // n1 bf16
    unsigned short* wt2 = wt1 + n1;                             // n2 bf16
    float* a_s  = (float*)(wt2 + n2 + ((n1 + n2) & 1));         // N f32 (align)
    float* a_d  = a_s + N;
    float* vecs = a_d + N;                                      // 384 f32
    float* cAs1 = vecs,       *cAd1 = vecs + 64,  *cB1 = vecs + 128;
    float* cAs2 = vecs + 192, *cAd2 = vecs + 256, *cB2 = vecs + 320;
    int* flags   = (int*)(vecs + 384);
    int* deg     = flags + 8;          // N
    int* cursor  = deg + N;            // N (contiguous with deg for one memset)
    int* row_ptr = cursor + N;         // N+1
    int* eidx    = row_ptr + N + 1;    // E+N

    int blkEdge = (total + 255) / 256;
    int blkPrep = (n1 + n2 + 384 + 255) / 256;
    int blkGemm = (N + 63) / 64;       // 4 waves x 16 rows per block
    int blkNode = (N + 3) / 4;

    detect_dtypes<<<1, 256, 0, stream>>>((const unsigned*)W1, (const unsigned*)ei, flags);
    prep_weights<<<blkPrep, 256, 0, stream>>>(W1, as1, ad1, b1, W2, as2, ad2, b2,
                                              wt1, wt2, vecs, n1, n2, K1, flags);

    // ---- CSR build (shared by both layers) ----
    hipMemsetAsync(deg, 0, 2 * N * sizeof(int), stream);
    hist_deg<<<blkEdge, 256, 0, stream>>>(ei, deg, E, N, flags);
    scan_deg<<<1, 1024, 0, stream>>>(deg, row_ptr, N);
    scatter_edges<<<blkEdge, 256, 0, stream>>>(ei, row_ptr, cursor, eidx, E, N, flags);

    // ---- layer 1 ----
    mfma_gemm<128><<<blkGemm, 256, 0, stream>>>(x, wt1, cAs1, cAd1, h, a_s, a_d, N, flags, 2);
    node_gather<<<blkNode, 256, 0, stream>>>(row_ptr, eidx, a_s, a_d, h, cB1, x1b, N, flags, 0);

    // ---- layer 2 ----
    mfma_gemm<64><<<blkGemm, 256, 0, stream>>>(x1b, wt2, cAs2, cAd2, h, a_s, a_d, N, flags, 1);
    node_gather<<<blkNode, 256, 0, stream>>>(row_ptr, eidx, a_s, a_d, h, cB2, d_out, N, flags, 1);
}

// Round 5
// 295.975 us; speedup vs baseline: 2.8911x; 1.2813x over previous
//
#include <hip/hip_runtime.h>
#include <hip/hip_bf16.h>

#define F_OUT 64
#define NEG_SLOPE 0.2f
#define SOFT_EPS 1e-16f

typedef short short8 __attribute__((ext_vector_type(8)));
typedef float floatx4 __attribute__((ext_vector_type(4)));

__device__ __forceinline__ unsigned short f2bf_bits(float v) {
    __hip_bfloat16 hb = __float2bfloat16(v);
    return *(unsigned short*)&hb;
}
__device__ __forceinline__ float bf_bits2f(unsigned short u) {
    __hip_bfloat16 hb = *(__hip_bfloat16*)&u;
    return __bfloat162float(hb);
}

// ---------- runtime dtype detection ----------
// flags[0] = 1 if float tensors are bf16, 0 if float32
// flags[1] = 1 if edge_index is int64, 0 if int32
__global__ void detect_dtypes(const unsigned* __restrict__ wbits,
                              const unsigned* __restrict__ ebits,
                              int* __restrict__ flags) {
    __shared__ int cnt_bf, cnt_zero;
    if (threadIdx.x == 0) { cnt_bf = 0; cnt_zero = 0; }
    __syncthreads();
    int lb = 0, lz = 0;
    for (int k = threadIdx.x; k < 4096; k += 256) {
        unsigned w = wbits[k];
        unsigned e = (w >> 7) & 0xFFu;
        if (e >= 0x60u && e <= 0x7Eu) lb++;
        if (ebits[2 * k + 1] == 0u) lz++;
    }
    atomicAdd(&cnt_bf, lb);
    atomicAdd(&cnt_zero, lz);
    __syncthreads();
    if (threadIdx.x == 0) {
        flags[0] = (cnt_bf > 2048) ? 1 : 0;
        flags[1] = (cnt_zero > 2048) ? 1 : 0;
    }
}

__device__ __forceinline__ float read_any(const void* src, int off, int bf) {
    return bf ? __bfloat162float(((const __hip_bfloat16*)src)[off])
              : ((const float*)src)[off];
}

// Transpose W1,W2 -> bf16 Wt[n][k]; convert att/bias vectors to f32.
__global__ void prep_weights(const void* w1, const void* as1, const void* ad1, const void* b1,
                             const void* w2, const void* as2, const void* ad2, const void* b2,
                             unsigned short* __restrict__ wt1, unsigned short* __restrict__ wt2,
                             float* __restrict__ vecs, int n1, int n2, int K1,
                             const int* __restrict__ flags) {
    int t = blockIdx.x * blockDim.x + threadIdx.x;
    int bf = flags[0];
    if (t < n1) {                       // wt1[n*K1 + k] = W1[k*64 + n]
        int n = t / K1, k = t - n * K1;
        wt1[t] = f2bf_bits(read_any(w1, k * F_OUT + n, bf));
    } else if (t < n1 + n2) {           // wt2[n*64 + k] = W2[k*64 + n]
        int u = t - n1;
        int n = u >> 6, k = u & 63;
        wt2[u] = f2bf_bits(read_any(w2, k * F_OUT + n, bf));
    } else if (t < n1 + n2 + 384) {
        int u = t - n1 - n2;
        const void* src[6] = {as1, ad1, b1, as2, ad2, b2};
        vecs[u] = read_any(src[u >> 6], u & 63, bf);
    }
}

__device__ __forceinline__ int get_idx(const void* ei, int i64, long long pos) {
    return i64 ? (int)((const long long*)ei)[pos] : ((const int*)ei)[pos];
}

// ---------- CSR build (by destination), self-loops appended at t >= E ----------
__global__ void hist_deg(const void* __restrict__ ei, int* __restrict__ deg,
                         int E, int N, const int* __restrict__ flags) {
    int t = blockIdx.x * blockDim.x + threadIdx.x;
    if (t >= E + N) return;
    int i64 = flags[1];
    int i = t < E ? get_idx(ei, i64, (long long)E + t) : t - E;
    atomicAdd(&deg[i], 1);
}

// ---- hierarchical exclusive scan of deg[0..N) -> row_ptr, cursor ----
// Phase A: per-1024-chunk sums. grid = nb = ceil(N/1024), block = 256.
__global__ void scan_phaseA(const int* __restrict__ deg, int* __restrict__ bsum, int N) {
    int idx = blockIdx.x * 1024 + threadIdx.x * 4;
    int s = 0;
#pragma unroll
    for (int j = 0; j < 4; ++j) { int k = idx + j; if (k < N) s += deg[k]; }
#pragma unroll
    for (int off = 1; off < 64; off <<= 1) s += __shfl_xor(s, off);
    __shared__ int ws[4];
    int lane = threadIdx.x & 63, w = threadIdx.x >> 6;
    if (lane == 0) ws[w] = s;
    __syncthreads();
    if (threadIdx.x == 0) bsum[blockIdx.x] = ws[0] + ws[1] + ws[2] + ws[3];
}

// Phase B: one wave scans bsum[0..nb) in place (exclusive); writes row_ptr[N]=total.
__global__ void scan_phaseB(int* __restrict__ bsum, int nb, int* __restrict__ row_ptr, int N) {
    int lane = threadIdx.x;  // 64 threads
    int carry = 0;
    for (int base = 0; base < nb; base += 64) {
        int idx = base + lane;
        int orig = (idx < nb) ? bsum[idx] : 0;
        int v = orig;
#pragma unroll
        for (int off = 1; off < 64; off <<= 1) {
            int t = __shfl_up(v, off);
            if (lane >= off) v += t;
        }
        int chunk_total = __shfl(v, 63);
        if (idx < nb) bsum[idx] = v - orig + carry;
        carry += chunk_total;
    }
    if (lane == 0) row_ptr[N] = carry;
}

// Phase C: block-local exclusive scan + block offset; writes row_ptr and cursor.
__global__ void scan_phaseC(const int* __restrict__ deg, const int* __restrict__ bsum,
                            int* __restrict__ row_ptr, int* __restrict__ cursor, int N) {
    int idx = blockIdx.x * 1024 + threadIdx.x * 4;
    int lane = threadIdx.x & 63, w = threadIdx.x >> 6;
    int d[4];
#pragma unroll
    for (int j = 0; j < 4; ++j) d[j] = (idx + j < N) ? deg[idx + j] : 0;
    int tot = d[0] + d[1] + d[2] + d[3];
    int v = tot;
#pragma unroll
    for (int off = 1; off < 64; off <<= 1) {
        int t = __shfl_up(v, off);
        if (lane >= off) v += t;
    }
    __shared__ int wtot[4];
    if (lane == 63) wtot[w] = v;
    __syncthreads();
    int woff = 0;
    for (int k = 0; k < w; ++k) woff += wtot[k];
    int excl = v - tot + woff + bsum[blockIdx.x];
    int o[4];
    o[0] = excl; o[1] = o[0] + d[0]; o[2] = o[1] + d[1]; o[3] = o[2] + d[2];
#pragma unroll
    for (int j = 0; j < 4; ++j)
        if (idx + j < N) { row_ptr[idx + j] = o[j]; cursor[idx + j] = o[j]; }
}

// cursor pre-seeded with row_ptr: atomicAdd return IS the write position.
__global__ void scatter_edges(const void* __restrict__ ei, int* __restrict__ cursor,
                              int* __restrict__ eidx, int E, int N,
                              const int* __restrict__ flags) {
    int t = blockIdx.x * blockDim.x + threadIdx.x;
    if (t >= E + N) return;
    int i64 = flags[1];
    int i = t < E ? get_idx(ei, i64, (long long)E + t) : t - E;
    int j = t < E ? get_idx(ei, i64, t) : t - E;
    int p = atomicAdd(&cursor[i], 1);
    eidx[p] = j;
}

// ---------- MFMA GEMM: h = x @ W (h stored bf16), fused attention dots ----------
// One wave = 16 rows x 64 cols. in_mode: 0=f32, 1=bf16, 2=consult flags[0].
template <int K>
__global__ void mfma_gemm(const void* __restrict__ xv, const unsigned short* __restrict__ Wt,
                          const float* __restrict__ att_s, const float* __restrict__ att_d,
                          unsigned short* __restrict__ h, float* __restrict__ a_s,
                          float* __restrict__ a_d, int N,
                          const int* __restrict__ flags, int in_mode) {
    int lane = threadIdx.x & 63;
    int m0 = (blockIdx.x * 4 + (threadIdx.x >> 6)) * 16;
    if (m0 >= N) return;
    int c = lane & 15, quad = lane >> 4;
    int arow = m0 + c;
    if (arow >= N) arow = N - 1;         // clamp loads; stores are guarded
    int bf = (in_mode == 2) ? flags[0] : in_mode;

    floatx4 acc0 = {0.f, 0.f, 0.f, 0.f};
    floatx4 acc1 = acc0, acc2 = acc0, acc3 = acc0;

    for (int kc = 0; kc < K; kc += 32) {
        int ka = kc + quad * 8;
        short8 a;
        if (bf) {
            a = *(const short8*)((const unsigned short*)xv + (size_t)arow * K + ka);
        } else {
            const float* xp = (const float*)xv + (size_t)arow * K + ka;
#pragma unroll
            for (int j = 0; j < 8; ++j) a[j] = (short)f2bf_bits(xp[j]);
        }
        short8 b0 = *(const short8*)(Wt + (size_t)(c)      * K + ka);
        short8 b1 = *(const short8*)(Wt + (size_t)(16 + c) * K + ka);
        short8 b2 = *(const short8*)(Wt + (size_t)(32 + c) * K + ka);
        short8 b3 = *(const short8*)(Wt + (size_t)(48 + c) * K + ka);
        acc0 = __builtin_amdgcn_mfma_f32_16x16x32_bf16(a, b0, acc0, 0, 0, 0);
        acc1 = __builtin_amdgcn_mfma_f32_16x16x32_bf16(a, b1, acc1, 0, 0, 0);
        acc2 = __builtin_amdgcn_mfma_f32_16x16x32_bf16(a, b2, acc2, 0, 0, 0);
        acc3 = __builtin_amdgcn_mfma_f32_16x16x32_bf16(a, b3, acc3, 0, 0, 0);
    }

    float as0 = att_s[c],      as1 = att_s[16 + c], as2 = att_s[32 + c], as3 = att_s[48 + c];
    float ad0 = att_d[c],      ad1 = att_d[16 + c], ad2 = att_d[32 + c], ad3 = att_d[48 + c];
#pragma unroll
    for (int reg = 0; reg < 4; ++reg) {
        int row = m0 + quad * 4 + reg;
        float vs = acc0[reg] * as0 + acc1[reg] * as1 + acc2[reg] * as2 + acc3[reg] * as3;
        float vd = acc0[reg] * ad0 + acc1[reg] * ad1 + acc2[reg] * ad2 + acc3[reg] * ad3;
#pragma unroll
        for (int off = 1; off < 16; off <<= 1) {
            vs += __shfl_xor(vs, off);
            vd += __shfl_xor(vd, off);
        }
        if (row < N) {
            if (c == 0) { a_s[row] = vs; a_d[row] = vd; }
            unsigned short* hr = h + (size_t)row * F_OUT + c;
            hr[0]  = f2bf_bits(acc0[reg]);
            hr[16] = f2bf_bits(acc1[reg]);
            hr[32] = f2bf_bits(acc2[reg]);
            hr[48] = f2bf_bits(acc3[reg]);
        }
    }
}

// ---------- fused softmax + gather + bias; 1 wave per node, 4-deep MLP ----------
// mode 0: x1_bf16 = bf16(relu(acc/sum + bias))
// mode 1: out = acc/sum + bias, stored bf16 or f32 per flags[0]
__global__ void node_gather(const int* __restrict__ row_ptr, const int* __restrict__ eidx,
                            const float* __restrict__ a_s, const float* __restrict__ a_d,
                            const unsigned short* __restrict__ h, const float* __restrict__ bias,
                            void* __restrict__ out, int N,
                            const int* __restrict__ flags, int mode) {
    int lane = threadIdx.x & 63;
    int i = blockIdx.x * 4 + (threadIdx.x >> 6);
    if (i >= N) return;
    int beg = row_ptr[i];
    int end = row_ptr[i + 1];
    float ad = a_d[i];
    float se = 0.f, acc = 0.f;
    int p = beg;
    for (; p + 4 <= end; p += 4) {
        int j0 = eidx[p], j1 = eidx[p + 1], j2 = eidx[p + 2], j3 = eidx[p + 3];
        float e0 = a_s[j0] + ad, e1 = a_s[j1] + ad;
        float e2 = a_s[j2] + ad, e3 = a_s[j3] + ad;
        float h0 = bf_bits2f(h[(size_t)j0 * F_OUT + lane]);
        float h1 = bf_bits2f(h[(size_t)j1 * F_OUT + lane]);
        float h2 = bf_bits2f(h[(size_t)j2 * F_OUT + lane]);
        float h3 = bf_bits2f(h[(size_t)j3 * F_OUT + lane]);
        float w0 = __expf(e0 > 0.f ? e0 : NEG_SLOPE * e0);
        float w1 = __expf(e1 > 0.f ? e1 : NEG_SLOPE * e1);
        float w2 = __expf(e2 > 0.f ? e2 : NEG_SLOPE * e2);
        float w3 = __expf(e3 > 0.f ? e3 : NEG_SLOPE * e3);
        se += (w0 + w1) + (w2 + w3);
        acc += (w0 * h0 + w1 * h1) + (w2 * h2 + w3 * h3);
    }
    for (; p < end; ++p) {
        int j = eidx[p];
        float e = a_s[j] + ad;
        float w = __expf(e > 0.f ? e : NEG_SLOPE * e);
        se += w;
        acc += w * bf_bits2f(h[(size_t)j * F_OUT + lane]);
    }
    float v = acc / (se + SOFT_EPS) + bias[lane];
    if (mode == 0) {
        ((unsigned short*)out)[(size_t)i * F_OUT + lane] = f2bf_bits(v > 0.f ? v : 0.f);
    } else {
        if (flags[0]) ((__hip_bfloat16*)out)[(size_t)i * F_OUT + lane] = __float2bfloat16(v);
        else          ((float*)out)[(size_t)i * F_OUT + lane] = v;
    }
}

extern "C" void kernel_launch(void* const* d_in, const int* in_sizes, int n_in,
                              void* d_out, int out_size, void* d_ws, size_t ws_size,
                              hipStream_t stream) {
    const void* x   = d_in[0];
    const void* ei  = d_in[1];
    const void* W1  = d_in[2];
    const void* as1 = d_in[3];
    const void* ad1 = d_in[4];
    const void* b1  = d_in[5];
    const void* W2  = d_in[6];
    const void* as2 = d_in[7];
    const void* ad2 = d_in[8];
    const void* b2  = d_in[9];

    int E  = in_sizes[1] / 2;          // 800000
    int n1 = in_sizes[2];              // 128*64
    int n2 = in_sizes[6];              // 64*64
    int K1 = n1 / F_OUT;               // 128
    int N  = in_sizes[0] / K1;         // 50000
    int total = E + N;
    int nb = (N + 1023) / 1024;        // scan chunks

    size_t nf = (size_t)N * F_OUT;
    char* wsb = (char*)d_ws;
    unsigned short* h   = (unsigned short*)wsb;                 // nf bf16
    unsigned short* x1b = h + nf;                               // nf bf16
    unsigned short* wt1 = x1b + nf;                             // n1 bf16
    unsigned short* wt2 = wt1 + n1;                             // n2 bf16
    float* a_s  = (float*)(wt2 + n2 + ((n1 + n2) & 1));         // N f32 (align)
    float* a_d  = a_s + N;
    float* vecs = a_d + N;                                      // 384 f32
    float* cAs1 = vecs,       *cAd1 = vecs + 64,  *cB1 = vecs + 128;
    float* cAs2 = vecs + 192, *cAd2 = vecs + 256, *cB2 = vecs + 320;
    int* flags   = (int*)(vecs + 384);
    int* deg     = flags + 8;          // N
    int* cursor  = deg + N;            // N
    int* row_ptr = cursor + N;         // N+1
    int* eidx    = row_ptr + N + 1;    // E+N
    int* bsum    = eidx + total;       // nb

    int blkEdge = (total + 255) / 256;
    int blkPrep = (n1 + n2 + 384 + 255) / 256;
    int blkGemm = (N + 63) / 64;       // 4 waves x 16 rows per block
    int blkNode = (N + 3) / 4;

    detect_dtypes<<<1, 256, 0, stream>>>((const unsigned*)W1, (const unsigned*)ei, flags);
    prep_weights<<<blkPrep, 256, 0, stream>>>(W1, as1, ad1, b1, W2, as2, ad2, b2,
                                              wt1, wt2, vecs, n1, n2, K1, flags);

    // ---- CSR build (shared by both layers) ----
    hipMemsetAsync(deg, 0, N * sizeof(int), stream);
    hist_deg<<<blkEdge, 256, 0, stream>>>(ei, deg, E, N, flags);
    scan_phaseA<<<nb, 256, 0, stream>>>(deg, bsum, N);
    scan_phaseB<<<1, 64, 0, stream>>>(bsum, nb, row_ptr, N);
    scan_phaseC<<<nb, 256, 0, stream>>>(deg, bsum, row_ptr, cursor, N);
    scatter_edges<<<blkEdge, 256, 0, stream>>>(ei, cursor, eidx, E, N, flags);

    // ---- layer 1 ----
    mfma_gemm<128><<<blkGemm, 256, 0, stream>>>(x, wt1, cAs1, cAd1, h, a_s, a_d, N, flags, 2);
    node_gather<<<blkNode, 256, 0, stream>>>(row_ptr, eidx, a_s, a_d, h, cB1, x1b, N, flags, 0);

    // ---- layer 2 ----
    mfma_gemm<64><<<blkGemm, 256, 0, stream>>>(x1b, wt2, cAs2, cAd2, h, a_s, a_d, N, flags, 1);
    node_gather<<<blkNode, 256, 0, stream>>>(row_ptr, eidx, a_s, a_d, h, cB2, d_out, N, flags, 1);
}

// Round 6
// 235.009 us; speedup vs baseline: 3.6411x; 1.2594x over previous
//
#include <hip/hip_runtime.h>
#include <hip/hip_bf16.h>

#define F_OUT 64
#define NEG_SLOPE 0.2f
#define SOFT_EPS 1e-16f
#define BW 256          // nodes per bucket (i_local fits in 8 bits)
#define CH 4096         // edges per chunk

typedef short short8 __attribute__((ext_vector_type(8)));
typedef float floatx4 __attribute__((ext_vector_type(4)));

__device__ __forceinline__ unsigned short f2bf_bits(float v) {
    __hip_bfloat16 hb = __float2bfloat16(v);
    return *(unsigned short*)&hb;
}
__device__ __forceinline__ float bf_bits2f(unsigned short u) {
    __hip_bfloat16 hb = *(__hip_bfloat16*)&u;
    return __bfloat162float(hb);
}

// ---------- runtime dtype detection ----------
// flags[0] = 1 if float tensors are bf16, 0 if float32
// flags[1] = 1 if edge_index is int64, 0 if int32
__global__ void detect_dtypes(const unsigned* __restrict__ wbits,
                              const unsigned* __restrict__ ebits,
                              int* __restrict__ flags) {
    __shared__ int cnt_bf, cnt_zero;
    if (threadIdx.x == 0) { cnt_bf = 0; cnt_zero = 0; }
    __syncthreads();
    int lb = 0, lz = 0;
    for (int k = threadIdx.x; k < 4096; k += 256) {
        unsigned w = wbits[k];
        unsigned e = (w >> 7) & 0xFFu;
        if (e >= 0x60u && e <= 0x7Eu) lb++;
        if (ebits[2 * k + 1] == 0u) lz++;
    }
    atomicAdd(&cnt_bf, lb);
    atomicAdd(&cnt_zero, lz);
    __syncthreads();
    if (threadIdx.x == 0) {
        flags[0] = (cnt_bf > 2048) ? 1 : 0;
        flags[1] = (cnt_zero > 2048) ? 1 : 0;
    }
}

__device__ __forceinline__ float read_any(const void* src, int off, int bf) {
    return bf ? __bfloat162float(((const __hip_bfloat16*)src)[off])
              : ((const float*)src)[off];
}

// Transpose W1,W2 -> bf16 Wt[n][k]; convert att/bias vectors to f32.
__global__ void prep_weights(const void* w1, const void* as1, const void* ad1, const void* b1,
                             const void* w2, const void* as2, const void* ad2, const void* b2,
                             unsigned short* __restrict__ wt1, unsigned short* __restrict__ wt2,
                             float* __restrict__ vecs, int n1, int n2, int K1,
                             const int* __restrict__ flags) {
    int t = blockIdx.x * blockDim.x + threadIdx.x;
    int bf = flags[0];
    if (t < n1) {                       // wt1[n*K1 + k] = W1[k*64 + n]
        int n = t / K1, k = t - n * K1;
        wt1[t] = f2bf_bits(read_any(w1, k * F_OUT + n, bf));
    } else if (t < n1 + n2) {           // wt2[n*64 + k] = W2[k*64 + n]
        int u = t - n1;
        int n = u >> 6, k = u & 63;
        wt2[u] = f2bf_bits(read_any(w2, k * F_OUT + n, bf));
    } else if (t < n1 + n2 + 384) {
        int u = t - n1 - n2;
        const void* src[6] = {as1, ad1, b1, as2, ad2, b2};
        vecs[u] = read_any(src[u >> 6], u & 63, bf);
    }
}

__device__ __forceinline__ int get_idx(const void* ei, int i64, long long pos) {
    return i64 ? (int)((const long long*)ei)[pos] : ((const int*)ei)[pos];
}

// ---------- locality-aware CSR build (counting sort by 256-node buckets) ----------
// Self-loops appended at t >= E (i = j = t - E).

// Per-chunk bucket histogram -> table[b * nchunks + chunk]  (bucket-major).
__global__ void bucket_count(const void* __restrict__ ei, int* __restrict__ table,
                             int E, int total, int NB, int nchunks,
                             const int* __restrict__ flags) {
    __shared__ int cnt[1024];
    for (int k = threadIdx.x; k < NB; k += 256) cnt[k] = 0;
    __syncthreads();
    int i64 = flags[1];
    int base = blockIdx.x * CH;
    int lim = base + CH < total ? base + CH : total;
    for (int t = base + threadIdx.x; t < lim; t += 256) {
        int i = t < E ? get_idx(ei, i64, (long long)E + t) : t - E;
        atomicAdd(&cnt[i >> 8], 1);
    }
    __syncthreads();
    for (int k = threadIdx.x; k < NB; k += 256) table[k * nchunks + blockIdx.x] = cnt[k];
}

// ---- generic hierarchical exclusive scan ----
__global__ void scan_phaseA(const int* __restrict__ src, int* __restrict__ bsum, int n) {
    int idx = blockIdx.x * 1024 + threadIdx.x * 4;
    int s = 0;
#pragma unroll
    for (int j = 0; j < 4; ++j) { int k = idx + j; if (k < n) s += src[k]; }
#pragma unroll
    for (int off = 1; off < 64; off <<= 1) s += __shfl_xor(s, off);
    __shared__ int ws[4];
    int lane = threadIdx.x & 63, w = threadIdx.x >> 6;
    if (lane == 0) ws[w] = s;
    __syncthreads();
    if (threadIdx.x == 0) bsum[blockIdx.x] = ws[0] + ws[1] + ws[2] + ws[3];
}

__global__ void scan_phaseB(int* __restrict__ bsum, int nb, int* __restrict__ total_out) {
    int lane = threadIdx.x;  // 64 threads
    int carry = 0;
    for (int base = 0; base < nb; base += 64) {
        int idx = base + lane;
        int orig = (idx < nb) ? bsum[idx] : 0;
        int v = orig;
#pragma unroll
        for (int off = 1; off < 64; off <<= 1) {
            int t = __shfl_up(v, off);
            if (lane >= off) v += t;
        }
        int chunk_total = __shfl(v, 63);
        if (idx < nb) bsum[idx] = v - orig + carry;
        carry += chunk_total;
    }
    if (lane == 0 && total_out) *total_out = carry;
}

// In-place safe: each block reads its own 1024 region before writing it.
__global__ void scan_phaseC(int* __restrict__ data, const int* __restrict__ bsum, int n) {
    int idx = blockIdx.x * 1024 + threadIdx.x * 4;
    int lane = threadIdx.x & 63, w = threadIdx.x >> 6;
    int d[4];
#pragma unroll
    for (int j = 0; j < 4; ++j) d[j] = (idx + j < n) ? data[idx + j] : 0;
    int tot = d[0] + d[1] + d[2] + d[3];
    int v = tot;
#pragma unroll
    for (int off = 1; off < 64; off <<= 1) {
        int t = __shfl_up(v, off);
        if (lane >= off) v += t;
    }
    __shared__ int wtot[4];
    if (lane == 63) wtot[w] = v;
    __syncthreads();
    int woff = 0;
    for (int k = 0; k < w; ++k) woff += wtot[k];
    int excl = v - tot + woff + bsum[blockIdx.x];
    int o[4];
    o[0] = excl; o[1] = o[0] + d[0]; o[2] = o[1] + d[1]; o[3] = o[2] + d[2];
#pragma unroll
    for (int j = 0; j < 4; ++j)
        if (idx + j < n) data[idx + j] = o[j];
}

// Per-chunk scatter into bucket-major staging: staged[pos] = (i_local<<24) | j.
// Cursors come from the scanned table; writes per bucket segment are contiguous.
__global__ void stage_scatter(const void* __restrict__ ei, const int* __restrict__ table,
                              unsigned* __restrict__ staged, int E, int total,
                              int NB, int nchunks, const int* __restrict__ flags) {
    __shared__ int cur[1024];
    for (int k = threadIdx.x; k < NB; k += 256) cur[k] = table[k * nchunks + blockIdx.x];
    __syncthreads();
    int i64 = flags[1];
    int base = blockIdx.x * CH;
    int lim = base + CH < total ? base + CH : total;
    for (int t = base + threadIdx.x; t < lim; t += 256) {
        int i = t < E ? get_idx(ei, i64, (long long)E + t) : t - E;
        int j = t < E ? get_idx(ei, i64, t) : t - E;
        int pos = atomicAdd(&cur[i >> 8], 1);
        staged[pos] = ((unsigned)(i & 255) << 24) | (unsigned)j;
    }
}

// One block per bucket: LDS degree hist -> LDS scan -> row_ptr (contiguous) and
// eidx scatter confined to this bucket's own segment (full-line writes).
__global__ void bucket_csr(const unsigned* __restrict__ staged, const int* __restrict__ table,
                           int* __restrict__ row_ptr, int* __restrict__ eidx,
                           int N, int total, int NB, int nchunks) {
    __shared__ int ldeg[BW];
    __shared__ int lcur[BW];
    __shared__ int wtot[4];
    int b = blockIdx.x;
    int t = threadIdx.x;
    int seg_beg = table[b * nchunks];
    int seg_end = (b + 1 < NB) ? table[(b + 1) * nchunks] : total;
    ldeg[t] = 0;
    __syncthreads();
    for (int p = seg_beg + t; p < seg_end; p += 256)
        atomicAdd(&ldeg[staged[p] >> 24], 1);
    __syncthreads();
    // exclusive scan of ldeg[0..255]
    int lane = t & 63, w = t >> 6;
    int d = ldeg[t];
    int v = d;
#pragma unroll
    for (int off = 1; off < 64; off <<= 1) {
        int u = __shfl_up(v, off);
        if (lane >= off) v += u;
    }
    if (lane == 63) wtot[w] = v;
    __syncthreads();
    int woff = 0;
    for (int k = 0; k < w; ++k) woff += wtot[k];
    int excl = v - d + woff;
    int node = b * BW + t;
    if (node < N) row_ptr[node] = seg_beg + excl;
    lcur[t] = excl;
    __syncthreads();
    for (int p = seg_beg + t; p < seg_end; p += 256) {
        unsigned pk = staged[p];
        int pos = atomicAdd(&lcur[pk >> 24], 1);
        eidx[seg_beg + pos] = (int)(pk & 0xFFFFFFu);
    }
}

// ---------- MFMA GEMM: h = x @ W (h stored bf16), fused attention dots ----------
// One wave = 16 rows x 64 cols. in_mode: 0=f32, 1=bf16, 2=consult flags[0].
template <int K>
__global__ void mfma_gemm(const void* __restrict__ xv, const unsigned short* __restrict__ Wt,
                          const float* __restrict__ att_s, const float* __restrict__ att_d,
                          unsigned short* __restrict__ h, float* __restrict__ a_s,
                          float* __restrict__ a_d, int N,
                          const int* __restrict__ flags, int in_mode) {
    int lane = threadIdx.x & 63;
    int m0 = (blockIdx.x * 4 + (threadIdx.x >> 6)) * 16;
    if (m0 >= N) return;
    int c = lane & 15, quad = lane >> 4;
    int arow = m0 + c;
    if (arow >= N) arow = N - 1;         // clamp loads; stores are guarded
    int bf = (in_mode == 2) ? flags[0] : in_mode;

    floatx4 acc0 = {0.f, 0.f, 0.f, 0.f};
    floatx4 acc1 = acc0, acc2 = acc0, acc3 = acc0;

    for (int kc = 0; kc < K; kc += 32) {
        int ka = kc + quad * 8;
        short8 a;
        if (bf) {
            a = *(const short8*)((const unsigned short*)xv + (size_t)arow * K + ka);
        } else {
            const float* xp = (const float*)xv + (size_t)arow * K + ka;
#pragma unroll
            for (int j = 0; j < 8; ++j) a[j] = (short)f2bf_bits(xp[j]);
        }
        short8 b0 = *(const short8*)(Wt + (size_t)(c)      * K + ka);
        short8 b1 = *(const short8*)(Wt + (size_t)(16 + c) * K + ka);
        short8 b2 = *(const short8*)(Wt + (size_t)(32 + c) * K + ka);
        short8 b3 = *(const short8*)(Wt + (size_t)(48 + c) * K + ka);
        acc0 = __builtin_amdgcn_mfma_f32_16x16x32_bf16(a, b0, acc0, 0, 0, 0);
        acc1 = __builtin_amdgcn_mfma_f32_16x16x32_bf16(a, b1, acc1, 0, 0, 0);
        acc2 = __builtin_amdgcn_mfma_f32_16x16x32_bf16(a, b2, acc2, 0, 0, 0);
        acc3 = __builtin_amdgcn_mfma_f32_16x16x32_bf16(a, b3, acc3, 0, 0, 0);
    }

    float as0 = att_s[c],      as1 = att_s[16 + c], as2 = att_s[32 + c], as3 = att_s[48 + c];
    float ad0 = att_d[c],      ad1 = att_d[16 + c], ad2 = att_d[32 + c], ad3 = att_d[48 + c];
#pragma unroll
    for (int reg = 0; reg < 4; ++reg) {
        int row = m0 + quad * 4 + reg;
        float vs = acc0[reg] * as0 + acc1[reg] * as1 + acc2[reg] * as2 + acc3[reg] * as3;
        float vd = acc0[reg] * ad0 + acc1[reg] * ad1 + acc2[reg] * ad2 + acc3[reg] * ad3;
#pragma unroll
        for (int off = 1; off < 16; off <<= 1) {
            vs += __shfl_xor(vs, off);
            vd += __shfl_xor(vd, off);
        }
        if (row < N) {
            if (c == 0) { a_s[row] = vs; a_d[row] = vd; }
            unsigned short* hr = h + (size_t)row * F_OUT + c;
            hr[0]  = f2bf_bits(acc0[reg]);
            hr[16] = f2bf_bits(acc1[reg]);
            hr[32] = f2bf_bits(acc2[reg]);
            hr[48] = f2bf_bits(acc3[reg]);
        }
    }
}

// ---------- fused softmax + gather + bias; 1 wave per node, 4-deep MLP ----------
// mode 0: x1_bf16 = bf16(relu(acc/sum + bias))
// mode 1: out = acc/sum + bias, stored bf16 or f32 per flags[0]
__global__ void node_gather(const int* __restrict__ row_ptr, const int* __restrict__ eidx,
                            const float* __restrict__ a_s, const float* __restrict__ a_d,
                            const unsigned short* __restrict__ h, const float* __restrict__ bias,
                            void* __restrict__ out, int N,
                            const int* __restrict__ flags, int mode) {
    int lane = threadIdx.x & 63;
    int i = blockIdx.x * 4 + (threadIdx.x >> 6);
    if (i >= N) return;
    int beg = row_ptr[i];
    int end = row_ptr[i + 1];
    float ad = a_d[i];
    float se = 0.f, acc = 0.f;
    int p = beg;
    for (; p + 4 <= end; p += 4) {
        int j0 = eidx[p], j1 = eidx[p + 1], j2 = eidx[p + 2], j3 = eidx[p + 3];
        float e0 = a_s[j0] + ad, e1 = a_s[j1] + ad;
        float e2 = a_s[j2] + ad, e3 = a_s[j3] + ad;
        float h0 = bf_bits2f(h[(size_t)j0 * F_OUT + lane]);
        float h1 = bf_bits2f(h[(size_t)j1 * F_OUT + lane]);
        float h2 = bf_bits2f(h[(size_t)j2 * F_OUT + lane]);
        float h3 = bf_bits2f(h[(size_t)j3 * F_OUT + lane]);
        float w0 = __expf(e0 > 0.f ? e0 : NEG_SLOPE * e0);
        float w1 = __expf(e1 > 0.f ? e1 : NEG_SLOPE * e1);
        float w2 = __expf(e2 > 0.f ? e2 : NEG_SLOPE * e2);
        float w3 = __expf(e3 > 0.f ? e3 : NEG_SLOPE * e3);
        se += (w0 + w1) + (w2 + w3);
        acc += (w0 * h0 + w1 * h1) + (w2 * h2 + w3 * h3);
    }
    for (; p < end; ++p) {
        int j = eidx[p];
        float e = a_s[j] + ad;
        float w = __expf(e > 0.f ? e : NEG_SLOPE * e);
        se += w;
        acc += w * bf_bits2f(h[(size_t)j * F_OUT + lane]);
    }
    float v = acc / (se + SOFT_EPS) + bias[lane];
    if (mode == 0) {
        ((unsigned short*)out)[(size_t)i * F_OUT + lane] = f2bf_bits(v > 0.f ? v : 0.f);
    } else {
        if (flags[0]) ((__hip_bfloat16*)out)[(size_t)i * F_OUT + lane] = __float2bfloat16(v);
        else          ((float*)out)[(size_t)i * F_OUT + lane] = v;
    }
}

extern "C" void kernel_launch(void* const* d_in, const int* in_sizes, int n_in,
                              void* d_out, int out_size, void* d_ws, size_t ws_size,
                              hipStream_t stream) {
    const void* x   = d_in[0];
    const void* ei  = d_in[1];
    const void* W1  = d_in[2];
    const void* as1 = d_in[3];
    const void* ad1 = d_in[4];
    const void* b1  = d_in[5];
    const void* W2  = d_in[6];
    const void* as2 = d_in[7];
    const void* ad2 = d_in[8];
    const void* b2  = d_in[9];

    int E  = in_sizes[1] / 2;          // 800000
    int n1 = in_sizes[2];              // 128*64
    int n2 = in_sizes[6];              // 64*64
    int K1 = n1 / F_OUT;               // 128
    int N  = in_sizes[0] / K1;         // 50000
    int total = E + N;
    int NB = (N + BW - 1) / BW;        // 196 buckets
    int nchunks = (total + CH - 1) / CH; // 208 chunks
    int M = NB * nchunks;              // table size
    int nbM = (M + 1023) / 1024;

    size_t nf = (size_t)N * F_OUT;
    char* wsb = (char*)d_ws;
    unsigned short* h   = (unsigned short*)wsb;                 // nf bf16
    unsigned short* x1b = h + nf;                               // nf bf16
    unsigned short* wt1 = x1b + nf;                             // n1 bf16
    unsigned short* wt2 = wt1 + n1;                             // n2 bf16
    float* a_s  = (float*)(wt2 + n2 + ((n1 + n2) & 1));         // N f32 (align)
    float* a_d  = a_s + N;
    float* vecs = a_d + N;                                      // 384 f32
    float* cAs1 = vecs,       *cAd1 = vecs + 64,  *cB1 = vecs + 128;
    float* cAs2 = vecs + 192, *cAd2 = vecs + 256, *cB2 = vecs + 320;
    int* flags    = (int*)(vecs + 384);
    int* row_ptr  = flags + 8;            // N+1
    int* eidx     = row_ptr + N + 1;      // total
    unsigned* staged = (unsigned*)(eidx + total); // total
    int* table    = (int*)(staged + total);       // M
    int* bsum     = table + M;                    // nbM

    int blkPrep = (n1 + n2 + 384 + 255) / 256;
    int blkGemm = (N + 63) / 64;       // 4 waves x 16 rows per block
    int blkNode = (N + 3) / 4;

    detect_dtypes<<<1, 256, 0, stream>>>((const unsigned*)W1, (const unsigned*)ei, flags);
    prep_weights<<<blkPrep, 256, 0, stream>>>(W1, as1, ad1, b1, W2, as2, ad2, b2,
                                              wt1, wt2, vecs, n1, n2, K1, flags);

    // ---- CSR build: bucket counting sort (no global atomics) ----
    bucket_count<<<nchunks, 256, 0, stream>>>(ei, table, E, total, NB, nchunks, flags);
    scan_phaseA<<<nbM, 256, 0, stream>>>(table, bsum, M);
    scan_phaseB<<<1, 64, 0, stream>>>(bsum, nbM, row_ptr + N);   // row_ptr[N] = E+N
    scan_phaseC<<<nbM, 256, 0, stream>>>(table, bsum, M);        // in-place exclusive scan
    stage_scatter<<<nchunks, 256, 0, stream>>>(ei, table, staged, E, total, NB, nchunks, flags);
    bucket_csr<<<NB, 256, 0, stream>>>(staged, table, row_ptr, eidx, N, total, NB, nchunks);

    // ---- layer 1 ----
    mfma_gemm<128><<<blkGemm, 256, 0, stream>>>(x, wt1, cAs1, cAd1, h, a_s, a_d, N, flags, 2);
    node_gather<<<blkNode, 256, 0, stream>>>(row_ptr, eidx, a_s, a_d, h, cB1, x1b, N, flags, 0);

    // ---- layer 2 ----
    mfma_gemm<64><<<blkGemm, 256, 0, stream>>>(x1b, wt2, cAs2, cAd2, h, a_s, a_d, N, flags, 1);
    node_gather<<<blkNode, 256, 0, stream>>>(row_ptr, eidx, a_s, a_d, h, cB2, d_out, N, flags, 1);
}

// Round 7
// 229.904 us; speedup vs baseline: 3.7219x; 1.0222x over previous
//
#include <hip/hip_runtime.h>
#include <hip/hip_bf16.h>

#define F_OUT 64
#define NEG_SLOPE 0.2f
#define SOFT_EPS 1e-16f
#define BW 256          // nodes per bucket (i_local fits in 8 bits)
#define CH 4096         // edges per chunk

typedef short short8 __attribute__((ext_vector_type(8)));
typedef float floatx4 __attribute__((ext_vector_type(4)));

__device__ __forceinline__ unsigned short f2bf_bits(float v) {
    __hip_bfloat16 hb = __float2bfloat16(v);
    return *(unsigned short*)&hb;
}
__device__ __forceinline__ float bf_bits2f(unsigned short u) {
    __hip_bfloat16 hb = *(__hip_bfloat16*)&u;
    return __bfloat162float(hb);
}

__device__ __forceinline__ float read_any(const void* src, int off, int bf) {
    return bf ? __bfloat162float(((const __hip_bfloat16*)src)[off])
              : ((const float*)src)[off];
}

// ---------- fused dtype detection + weight prep (single block) ----------
// flags[0] = 1 if float tensors are bf16, 0 if float32
// flags[1] = 1 if edge_index is int64, 0 if int32
// Then: transpose W1,W2 -> bf16 Wt[n][k]; att/bias vectors -> f32.
__global__ void prep_all(const unsigned* __restrict__ wbits, const unsigned* __restrict__ ebits,
                         const void* w1, const void* as1, const void* ad1, const void* b1,
                         const void* w2, const void* as2, const void* ad2, const void* b2,
                         unsigned short* __restrict__ wt1, unsigned short* __restrict__ wt2,
                         float* __restrict__ vecs, int n1, int n2, int K1,
                         int* __restrict__ flags) {
    __shared__ int cnt_bf, cnt_zero, sh_bf;
    int tid = threadIdx.x;
    if (tid == 0) { cnt_bf = 0; cnt_zero = 0; }
    __syncthreads();
    int lb = 0, lz = 0;
    for (int k = tid; k < 4096; k += 1024) {
        unsigned w = wbits[k];
        unsigned e = (w >> 7) & 0xFFu;
        if (e >= 0x60u && e <= 0x7Eu) lb++;
        if (ebits[2 * k + 1] == 0u) lz++;
    }
    atomicAdd(&cnt_bf, lb);
    atomicAdd(&cnt_zero, lz);
    __syncthreads();
    if (tid == 0) {
        int bf = (cnt_bf > 2048) ? 1 : 0;
        flags[0] = bf;
        flags[1] = (cnt_zero > 2048) ? 1 : 0;
        sh_bf = bf;
    }
    __syncthreads();
    int bf = sh_bf;
    int total = n1 + n2 + 384;
    for (int t = tid; t < total; t += 1024) {
        if (t < n1) {                       // wt1[n*K1 + k] = W1[k*64 + n]
            int n = t / K1, k = t - n * K1;
            wt1[t] = f2bf_bits(read_any(w1, k * F_OUT + n, bf));
        } else if (t < n1 + n2) {           // wt2[n*64 + k] = W2[k*64 + n]
            int u = t - n1;
            int n = u >> 6, k = u & 63;
            wt2[u] = f2bf_bits(read_any(w2, k * F_OUT + n, bf));
        } else {
            int u = t - n1 - n2;
            const void* src[6] = {as1, ad1, b1, as2, ad2, b2};
            vecs[u] = read_any(src[u >> 6], u & 63, bf);
        }
    }
}

__device__ __forceinline__ int get_idx(const void* ei, int i64, long long pos) {
    return i64 ? (int)((const long long*)ei)[pos] : ((const int*)ei)[pos];
}

// ---------- locality-aware CSR build (counting sort by 256-node buckets) ----------
// Self-loops appended at t >= E (i = j = t - E).

// Per-chunk bucket histogram -> table[b * nchunks + chunk]  (bucket-major).
__global__ void bucket_count(const void* __restrict__ ei, int* __restrict__ table,
                             int E, int total, int NB, int nchunks,
                             const int* __restrict__ flags) {
    __shared__ int cnt[1024];
    for (int k = threadIdx.x; k < NB; k += 256) cnt[k] = 0;
    __syncthreads();
    int i64 = flags[1];
    int base = blockIdx.x * CH;
    int lim = base + CH < total ? base + CH : total;
    for (int t = base + threadIdx.x; t < lim; t += 256) {
        int i = t < E ? get_idx(ei, i64, (long long)E + t) : t - E;
        atomicAdd(&cnt[i >> 8], 1);
    }
    __syncthreads();
    for (int k = threadIdx.x; k < NB; k += 256) table[k * nchunks + blockIdx.x] = cnt[k];
}

// ---- generic hierarchical exclusive scan ----
__global__ void scan_phaseA(const int* __restrict__ src, int* __restrict__ bsum, int n) {
    int idx = blockIdx.x * 1024 + threadIdx.x * 4;
    int s = 0;
#pragma unroll
    for (int j = 0; j < 4; ++j) { int k = idx + j; if (k < n) s += src[k]; }
#pragma unroll
    for (int off = 1; off < 64; off <<= 1) s += __shfl_xor(s, off);
    __shared__ int ws[4];
    int lane = threadIdx.x & 63, w = threadIdx.x >> 6;
    if (lane == 0) ws[w] = s;
    __syncthreads();
    if (threadIdx.x == 0) bsum[blockIdx.x] = ws[0] + ws[1] + ws[2] + ws[3];
}

__global__ void scan_phaseB(int* __restrict__ bsum, int nb, int* __restrict__ total_out) {
    int lane = threadIdx.x;  // 64 threads
    int carry = 0;
    for (int base = 0; base < nb; base += 64) {
        int idx = base + lane;
        int orig = (idx < nb) ? bsum[idx] : 0;
        int v = orig;
#pragma unroll
        for (int off = 1; off < 64; off <<= 1) {
            int t = __shfl_up(v, off);
            if (lane >= off) v += t;
        }
        int chunk_total = __shfl(v, 63);
        if (idx < nb) bsum[idx] = v - orig + carry;
        carry += chunk_total;
    }
    if (lane == 0 && total_out) *total_out = carry;
}

// In-place safe: each block reads its own 1024 region before writing it.
__global__ void scan_phaseC(int* __restrict__ data, const int* __restrict__ bsum, int n) {
    int idx = blockIdx.x * 1024 + threadIdx.x * 4;
    int lane = threadIdx.x & 63, w = threadIdx.x >> 6;
    int d[4];
#pragma unroll
    for (int j = 0; j < 4; ++j) d[j] = (idx + j < n) ? data[idx + j] : 0;
    int tot = d[0] + d[1] + d[2] + d[3];
    int v = tot;
#pragma unroll
    for (int off = 1; off < 64; off <<= 1) {
        int t = __shfl_up(v, off);
        if (lane >= off) v += t;
    }
    __shared__ int wtot[4];
    if (lane == 63) wtot[w] = v;
    __syncthreads();
    int woff = 0;
    for (int k = 0; k < w; ++k) woff += wtot[k];
    int excl = v - tot + woff + bsum[blockIdx.x];
    int o[4];
    o[0] = excl; o[1] = o[0] + d[0]; o[2] = o[1] + d[1]; o[3] = o[2] + d[2];
#pragma unroll
    for (int j = 0; j < 4; ++j)
        if (idx + j < n) data[idx + j] = o[j];
}

// Per-chunk scatter into bucket-major staging: staged[pos] = (i_local<<24) | j.
__global__ void stage_scatter(const void* __restrict__ ei, const int* __restrict__ table,
                              unsigned* __restrict__ staged, int E, int total,
                              int NB, int nchunks, const int* __restrict__ flags) {
    __shared__ int cur[1024];
    for (int k = threadIdx.x; k < NB; k += 256) cur[k] = table[k * nchunks + blockIdx.x];
    __syncthreads();
    int i64 = flags[1];
    int base = blockIdx.x * CH;
    int lim = base + CH < total ? base + CH : total;
    for (int t = base + threadIdx.x; t < lim; t += 256) {
        int i = t < E ? get_idx(ei, i64, (long long)E + t) : t - E;
        int j = t < E ? get_idx(ei, i64, t) : t - E;
        int pos = atomicAdd(&cur[i >> 8], 1);
        staged[pos] = ((unsigned)(i & 255) << 24) | (unsigned)j;
    }
}

// One block per bucket: LDS degree hist -> LDS scan -> row_ptr and in-segment eidx.
__global__ void bucket_csr(const unsigned* __restrict__ staged, const int* __restrict__ table,
                           int* __restrict__ row_ptr, int* __restrict__ eidx,
                           int N, int total, int NB, int nchunks) {
    __shared__ int ldeg[BW];
    __shared__ int lcur[BW];
    __shared__ int wtot[4];
    int b = blockIdx.x;
    int t = threadIdx.x;
    int seg_beg = table[b * nchunks];
    int seg_end = (b + 1 < NB) ? table[(b + 1) * nchunks] : total;
    ldeg[t] = 0;
    __syncthreads();
    for (int p = seg_beg + t; p < seg_end; p += 256)
        atomicAdd(&ldeg[staged[p] >> 24], 1);
    __syncthreads();
    int lane = t & 63, w = t >> 6;
    int d = ldeg[t];
    int v = d;
#pragma unroll
    for (int off = 1; off < 64; off <<= 1) {
        int u = __shfl_up(v, off);
        if (lane >= off) v += u;
    }
    if (lane == 63) wtot[w] = v;
    __syncthreads();
    int woff = 0;
    for (int k = 0; k < w; ++k) woff += wtot[k];
    int excl = v - d + woff;
    int node = b * BW + t;
    if (node < N) row_ptr[node] = seg_beg + excl;
    lcur[t] = excl;
    __syncthreads();
    for (int p = seg_beg + t; p < seg_end; p += 256) {
        unsigned pk = staged[p];
        int pos = atomicAdd(&lcur[pk >> 24], 1);
        eidx[seg_beg + pos] = (int)(pk & 0xFFFFFFu);
    }
}

// ---------- MFMA GEMM: h = x @ W (h stored bf16), fused attention dots ----------
template <int K>
__global__ void mfma_gemm(const void* __restrict__ xv, const unsigned short* __restrict__ Wt,
                          const float* __restrict__ att_s, const float* __restrict__ att_d,
                          unsigned short* __restrict__ h, float* __restrict__ a_s,
                          float* __restrict__ a_d, int N,
                          const int* __restrict__ flags, int in_mode) {
    int lane = threadIdx.x & 63;
    int m0 = (blockIdx.x * 4 + (threadIdx.x >> 6)) * 16;
    if (m0 >= N) return;
    int c = lane & 15, quad = lane >> 4;
    int arow = m0 + c;
    if (arow >= N) arow = N - 1;
    int bf = (in_mode == 2) ? flags[0] : in_mode;

    floatx4 acc0 = {0.f, 0.f, 0.f, 0.f};
    floatx4 acc1 = acc0, acc2 = acc0, acc3 = acc0;

    for (int kc = 0; kc < K; kc += 32) {
        int ka = kc + quad * 8;
        short8 a;
        if (bf) {
            a = *(const short8*)((const unsigned short*)xv + (size_t)arow * K + ka);
        } else {
            const float* xp = (const float*)xv + (size_t)arow * K + ka;
#pragma unroll
            for (int j = 0; j < 8; ++j) a[j] = (short)f2bf_bits(xp[j]);
        }
        short8 b0 = *(const short8*)(Wt + (size_t)(c)      * K + ka);
        short8 b1 = *(const short8*)(Wt + (size_t)(16 + c) * K + ka);
        short8 b2 = *(const short8*)(Wt + (size_t)(32 + c) * K + ka);
        short8 b3 = *(const short8*)(Wt + (size_t)(48 + c) * K + ka);
        acc0 = __builtin_amdgcn_mfma_f32_16x16x32_bf16(a, b0, acc0, 0, 0, 0);
        acc1 = __builtin_amdgcn_mfma_f32_16x16x32_bf16(a, b1, acc1, 0, 0, 0);
        acc2 = __builtin_amdgcn_mfma_f32_16x16x32_bf16(a, b2, acc2, 0, 0, 0);
        acc3 = __builtin_amdgcn_mfma_f32_16x16x32_bf16(a, b3, acc3, 0, 0, 0);
    }

    float as0 = att_s[c],      as1 = att_s[16 + c], as2 = att_s[32 + c], as3 = att_s[48 + c];
    float ad0 = att_d[c],      ad1 = att_d[16 + c], ad2 = att_d[32 + c], ad3 = att_d[48 + c];
#pragma unroll
    for (int reg = 0; reg < 4; ++reg) {
        int row = m0 + quad * 4 + reg;
        float vs = acc0[reg] * as0 + acc1[reg] * as1 + acc2[reg] * as2 + acc3[reg] * as3;
        float vd = acc0[reg] * ad0 + acc1[reg] * ad1 + acc2[reg] * ad2 + acc3[reg] * ad3;
#pragma unroll
        for (int off = 1; off < 16; off <<= 1) {
            vs += __shfl_xor(vs, off);
            vd += __shfl_xor(vd, off);
        }
        if (row < N) {
            if (c == 0) { a_s[row] = vs; a_d[row] = vd; }
            unsigned short* hr = h + (size_t)row * F_OUT + c;
            hr[0]  = f2bf_bits(acc0[reg]);
            hr[16] = f2bf_bits(acc1[reg]);
            hr[32] = f2bf_bits(acc2[reg]);
            hr[48] = f2bf_bits(acc3[reg]);
        }
    }
}

// ---------- fused softmax + gather + bias; 1 wave per node ----------
// Lane-parallel edge metadata: lane e of a 64-edge tile loads eidx/a_s and
// computes w once; feature loop broadcasts (j,w) via shuffles. Per-edge cost:
// 1 vector h-load + 2 LDS-pipe shuffles (vs 3 VMEM + 64-wide exp before).
// mode 0: x1_bf16 = bf16(relu(acc/sum + bias))
// mode 1: out = acc/sum + bias, stored bf16 or f32 per flags[0]
__global__ void node_gather(const int* __restrict__ row_ptr, const int* __restrict__ eidx,
                            const float* __restrict__ a_s, const float* __restrict__ a_d,
                            const unsigned short* __restrict__ h, const float* __restrict__ bias,
                            void* __restrict__ out, int N,
                            const int* __restrict__ flags, int mode) {
    int lane = threadIdx.x & 63;
    int i = blockIdx.x * 4 + (threadIdx.x >> 6);
    if (i >= N) return;
    int beg = row_ptr[i];
    int end = row_ptr[i + 1];
    float ad = a_d[i];
    float se = 0.f;
    float acc0 = 0.f, acc1 = 0.f, acc2 = 0.f, acc3 = 0.f;
    for (int p = beg; p < end; p += 64) {
        int tile = end - p; if (tile > 64) tile = 64;
        int j = eidx[p + (lane < tile ? lane : tile - 1)];
        float w = 0.f;
        if (lane < tile) {
            float e = a_s[j] + ad;
            w = __expf(e > 0.f ? e : NEG_SLOPE * e);
        }
        se += w;
        int e = 0;
        for (; e + 4 <= tile; e += 4) {
            int j0 = __shfl(j, e),     j1 = __shfl(j, e + 1);
            int j2 = __shfl(j, e + 2), j3 = __shfl(j, e + 3);
            float w0 = __shfl(w, e),     w1 = __shfl(w, e + 1);
            float w2 = __shfl(w, e + 2), w3 = __shfl(w, e + 3);
            float h0 = bf_bits2f(h[(size_t)j0 * F_OUT + lane]);
            float h1 = bf_bits2f(h[(size_t)j1 * F_OUT + lane]);
            float h2 = bf_bits2f(h[(size_t)j2 * F_OUT + lane]);
            float h3 = bf_bits2f(h[(size_t)j3 * F_OUT + lane]);
            acc0 += w0 * h0; acc1 += w1 * h1; acc2 += w2 * h2; acc3 += w3 * h3;
        }
        for (; e < tile; ++e) {
            int jj = __shfl(j, e);
            float ww = __shfl(w, e);
            acc0 += ww * bf_bits2f(h[(size_t)jj * F_OUT + lane]);
        }
    }
#pragma unroll
    for (int off = 1; off < 64; off <<= 1) se += __shfl_xor(se, off);
    float acc = (acc0 + acc1) + (acc2 + acc3);
    float v = acc / (se + SOFT_EPS) + bias[lane];
    if (mode == 0) {
        ((unsigned short*)out)[(size_t)i * F_OUT + lane] = f2bf_bits(v > 0.f ? v : 0.f);
    } else {
        if (flags[0]) ((__hip_bfloat16*)out)[(size_t)i * F_OUT + lane] = __float2bfloat16(v);
        else          ((float*)out)[(size_t)i * F_OUT + lane] = v;
    }
}

extern "C" void kernel_launch(void* const* d_in, const int* in_sizes, int n_in,
                              void* d_out, int out_size, void* d_ws, size_t ws_size,
                              hipStream_t stream) {
    const void* x   = d_in[0];
    const void* ei  = d_in[1];
    const void* W1  = d_in[2];
    const void* as1 = d_in[3];
    const void* ad1 = d_in[4];
    const void* b1  = d_in[5];
    const void* W2  = d_in[6];
    const void* as2 = d_in[7];
    const void* ad2 = d_in[8];
    const void* b2  = d_in[9];

    int E  = in_sizes[1] / 2;          // 800000
    int n1 = in_sizes[2];              // 128*64
    int n2 = in_sizes[6];              // 64*64
    int K1 = n1 / F_OUT;               // 128
    int N  = in_sizes[0] / K1;         // 50000
    int total = E + N;
    int NB = (N + BW - 1) / BW;        // 196 buckets
    int nchunks = (total + CH - 1) / CH; // 208 chunks
    int M = NB * nchunks;              // table size
    int nbM = (M + 1023) / 1024;

    size_t nf = (size_t)N * F_OUT;
    char* wsb = (char*)d_ws;
    unsigned short* h   = (unsigned short*)wsb;                 // nf bf16
    unsigned short* x1b = h + nf;                               // nf bf16
    unsigned short* wt1 = x1b + nf;                             // n1 bf16
    unsigned short* wt2 = wt1 + n1;                             // n2 bf16
    float* a_s  = (float*)(wt2 + n2 + ((n1 + n2) & 1));         // N f32 (align)
    float* a_d  = a_s + N;
    float* vecs = a_d + N;                                      // 384 f32
    float* cAs1 = vecs,       *cAd1 = vecs + 64,  *cB1 = vecs + 128;
    float* cAs2 = vecs + 192, *cAd2 = vecs + 256, *cB2 = vecs + 320;
    int* flags    = (int*)(vecs + 384);
    int* row_ptr  = flags + 8;            // N+1
    int* eidx     = row_ptr + N + 1;      // total
    unsigned* staged = (unsigned*)(eidx + total); // total
    int* table    = (int*)(staged + total);       // M
    int* bsum     = table + M;                    // nbM

    int blkGemm = (N + 63) / 64;       // 4 waves x 16 rows per block
    int blkNode = (N + 3) / 4;

    prep_all<<<1, 1024, 0, stream>>>((const unsigned*)W1, (const unsigned*)ei,
                                     W1, as1, ad1, b1, W2, as2, ad2, b2,
                                     wt1, wt2, vecs, n1, n2, K1, flags);

    // ---- CSR build: bucket counting sort (no global atomics) ----
    bucket_count<<<nchunks, 256, 0, stream>>>(ei, table, E, total, NB, nchunks, flags);
    scan_phaseA<<<nbM, 256, 0, stream>>>(table, bsum, M);
    scan_phaseB<<<1, 64, 0, stream>>>(bsum, nbM, row_ptr + N);   // row_ptr[N] = E+N
    scan_phaseC<<<nbM, 256, 0, stream>>>(table, bsum, M);        // in-place exclusive scan
    stage_scatter<<<nchunks, 256, 0, stream>>>(ei, table, staged, E, total, NB, nchunks, flags);
    bucket_csr<<<NB, 256, 0, stream>>>(staged, table, row_ptr, eidx, N, total, NB, nchunks);

    // ---- layer 1 ----
    mfma_gemm<128><<<blkGemm, 256, 0, stream>>>(x, wt1, cAs1, cAd1, h, a_s, a_d, N, flags, 2);
    node_gather<<<blkNode, 256, 0, stream>>>(row_ptr, eidx, a_s, a_d, h, cB1, x1b, N, flags, 0);

    // ---- layer 2 ----
    mfma_gemm<64><<<blkGemm, 256, 0, stream>>>(x1b, wt2, cAs2, cAd2, h, a_s, a_d, N, flags, 1);
    node_gather<<<blkNode, 256, 0, stream>>>(row_ptr, eidx, a_s, a_d, h, cB2, d_out, N, flags, 1);
}